// Round 14
// baseline (1095.350 us; speedup 1.0000x reference)
//
#include <hip/hip_runtime.h>
#include <hip/hip_bf16.h>
#include <math.h>

constexpr int NN  = 16384;
constexpr int DD  = 64;
constexpr int CC  = 128;
constexpr int OO  = 128;
constexpr int KP1 = 17;
constexpr int NT  = 256;             // 64-col tiles per row
constexpr int CAP = 256;             // candidate cap per row

typedef __attribute__((ext_vector_type(8))) short short8;
typedef __attribute__((ext_vector_type(4))) float floatx4;

__device__ __forceinline__ float bf2f(unsigned short u) {
    union { unsigned u; float f; } c; c.u = ((unsigned)u) << 16; return c.f;
}
__device__ __forceinline__ unsigned short f2bf(float f) {
    union { float f; unsigned u; } c; c.f = f;
    unsigned b = c.u;
    return (unsigned short)((b + 0x7FFFu + ((b >> 16) & 1u)) >> 16);
}

// ---------------------------------------------------------------------------
// Shared 128x128 MFMA tile: identical code in k_simmax and k_cand ->
// bit-identical fp32 accumulators (MFMA deterministic, fixed chain order).
// ---------------------------------------------------------------------------
__device__ __forceinline__ void gemm128(const unsigned short* __restrict__ znb,
                                        int am0, int bn0, int lane, int wv,
                                        floatx4 (&acc)[4][4])
{
    const int mq = (wv & 1) * 64;
    const int nq = (wv >> 1) * 64;
    const int lm = lane & 15;
    const int lk = lane >> 4;

    short8 af[4][4];   // [kt][mt]
    #pragma unroll
    for (int mt = 0; mt < 4; mt++) {
        const unsigned short* ap = znb + (size_t)(am0 + mq + mt * 16 + lm) * CC;
        #pragma unroll
        for (int kt = 0; kt < 4; kt++)
            af[kt][mt] = *(const short8*)&ap[kt * 32 + lk * 8];
    }
    #pragma unroll
    for (int i = 0; i < 4; i++)
        #pragma unroll
        for (int j = 0; j < 4; j++) acc[i][j] = (floatx4){0.f, 0.f, 0.f, 0.f};

    #pragma unroll
    for (int nt = 0; nt < 4; nt++) {
        const unsigned short* bp = znb + (size_t)(bn0 + nq + nt * 16 + lm) * CC;
        #pragma unroll
        for (int kt = 0; kt < 4; kt++) {
            short8 bf8 = *(const short8*)&bp[kt * 32 + lk * 8];
            #pragma unroll
            for (int mt = 0; mt < 4; mt++)
                acc[mt][nt] = __builtin_amdgcn_mfma_f32_16x16x32_bf16(
                    af[kt][mt], bf8, acc[mt][nt], 0, 0, 0);
        }
    }
}

// ---------------------------------------------------------------------------
// Init: deg = 0, ccnt = 0, nbr = self
// ---------------------------------------------------------------------------
__global__ __launch_bounds__(256)
void k_init(int* __restrict__ deg, int* __restrict__ ccnt, int* __restrict__ nbr)
{
    int t = blockIdx.x * 256 + threadIdx.x;
    if (t < NN) { deg[t] = 0; ccnt[t] = 0; }
    if (t < NN * KP1) nbr[t] = t / KP1;
}

// ---------------------------------------------------------------------------
// Preprocess: 8 nodes/block, 128 threads (thread = channel), fp64 math.
// ---------------------------------------------------------------------------
__global__ __launch_bounds__(128)
void k_pre(const float* __restrict__ x_raw, const float* __restrict__ eps,
           const float* __restrict__ col_logit, const float* __restrict__ type_logit,
           const float* __restrict__ W_enc, const float* __restrict__ b_enc,
           const float* __restrict__ W_mu, const float* __restrict__ b_mu,
           const float* __restrict__ W_lv, const float* __restrict__ b_lv,
           double* __restrict__ zn64, float* __restrict__ z32, float* __restrict__ zn32,
           unsigned short* __restrict__ znb, int use64)
{
    const int tid = threadIdx.x;
    const int n0  = blockIdx.x * 8;
    __shared__ double xg[8][DD];
    __shared__ double hs[8][CC];
    __shared__ double zs[8][CC];
    __shared__ double part[8][16];
    __shared__ double rs_s[8];
    __shared__ double gcol[DD];

    if (tid < DD) {
        double l = (double)col_logit[tid];
        double s = 1.0 / (1.0 + exp(-l * 0.5));
        gcol[tid] = fmin(fmax(s * 1.2 - 0.1, 0.0), 1.0);
    }
    __syncthreads();

    #pragma unroll
    for (int rpt = 0; rpt < 4; rpt++) {
        int idx = tid + rpt * 128;
        int m = idx >> 6, d = idx & 63;
        xg[m][d] = (double)x_raw[(size_t)(n0 + m) * DD + d] * gcol[d];
    }
    __syncthreads();

    double tg;
    {
        double l = (double)type_logit[0];
        double s = 1.0 / (1.0 + exp(-l * 0.5));
        tg = fmin(fmax(s * 1.2 - 0.1, 0.0), 1.0);
    }

    double h[8];
    #pragma unroll
    for (int m = 0; m < 8; m++) h[m] = (double)b_enc[tid];
    for (int d = 0; d < DD; d++) {
        double w = (double)W_enc[d * CC + tid];
        #pragma unroll
        for (int m = 0; m < 8; m++) h[m] += xg[m][d] * w;
    }
    #pragma unroll
    for (int m = 0; m < 8; m++) hs[m][tid] = h[m] * tg;
    __syncthreads();

    double mu[8], lv[8];
    #pragma unroll
    for (int m = 0; m < 8; m++) { mu[m] = (double)b_mu[tid]; lv[m] = (double)b_lv[tid]; }
    for (int j = 0; j < CC; j++) {
        double wm = (double)W_mu[j * CC + tid];
        double wl = (double)W_lv[j * CC + tid];
        #pragma unroll
        for (int m = 0; m < 8; m++) { double hj = hs[m][j]; mu[m] += hj * wm; lv[m] += hj * wl; }
    }
    #pragma unroll
    for (int m = 0; m < 8; m++) {
        double l = fmin(fmax(lv[m], -10.0), 10.0);
        zs[m][tid] = mu[m] + (double)eps[(size_t)(n0 + m) * CC + tid] * exp(0.5 * l);
    }
    __syncthreads();

    {
        int m = tid >> 4, t = tid & 15;
        double s = 0.0;
        for (int c = t; c < CC; c += 16) { double z = zs[m][c]; s += z * z; }
        part[m][t] = s;
    }
    __syncthreads();
    if (tid < 8) {
        double s = 0.0;
        for (int t = 0; t < 16; t++) s += part[tid][t];
        rs_s[tid] = 1.0 / sqrt(s + 1e-12);
    }
    __syncthreads();

    #pragma unroll
    for (int m = 0; m < 8; m++) {
        double z  = zs[m][tid];
        double zn = z * rs_s[m];
        size_t o  = (size_t)(n0 + m) * CC + tid;
        if (use64) zn64[o] = zn;
        z32[o]  = (float)z;
        float znf = (float)zn;
        zn32[o] = znf;
        znb[o]  = f2bf(znf);
    }
}

// ---------------------------------------------------------------------------
// Pass 1: tile maxes only (raw fp32 acc). Grid (128,128).
// ---------------------------------------------------------------------------
__global__ __launch_bounds__(256)
void k_simmax(const unsigned short* __restrict__ znb, float* __restrict__ simmax)
{
    const int tid  = threadIdx.x;
    const int lane = tid & 63;
    const int wv   = tid >> 6;
    const int am0  = blockIdx.x * 128;
    const int bn0  = blockIdx.y * 128;
    const int mq   = (wv & 1) * 64;
    const int lm   = lane & 15;
    const int lk   = lane >> 4;

    floatx4 acc[4][4];
    gemm128(znb, am0, bn0, lane, wv, acc);

    #pragma unroll
    for (int mt = 0; mt < 4; mt++)
        #pragma unroll
        for (int rg = 0; rg < 4; rg++) {
            int m = mq + mt * 16 + lk * 4 + rg;
            float mx = acc[mt][0][rg];
            #pragma unroll
            for (int nt = 1; nt < 4; nt++) mx = fmaxf(mx, acc[mt][nt][rg]);
            #pragma unroll
            for (int s = 1; s < 16; s <<= 1) mx = fmaxf(mx, __shfl_xor(mx, s));
            if (lm == 0) {
                int row = am0 + m;
                int gtile = blockIdx.y * 2 + (wv >> 1);
                simmax[(size_t)row * NT + gtile] = mx;
            }
        }
}

// ---------------------------------------------------------------------------
// L[row] = 32nd-largest tile max. The 32 largest tile maxes are 32 distinct
// elements >= L, so the 32nd-largest element >= L; candidates >= L-eps
// therefore cover the acc-top-32, whose fp64-margin to the true top-17 is
// ~17 order-stat gaps (~1.8e-2) >> bf16-acc noise (~1e-3). [R13 ERRATA: with
// the 17th tile max the margin was ~0 and rows flipped.]
// ---------------------------------------------------------------------------
__global__ __launch_bounds__(256)
void k_thresh(const float* __restrict__ simmax, float* __restrict__ Lrow)
{
    const int r = blockIdx.x;
    const int tid = threadIdx.x;
    __shared__ float smax[NT];
    smax[tid] = simmax[(size_t)r * NT + tid];
    __syncthreads();
    float v = smax[tid];
    int rank = 0;
    for (int j = 0; j < NT; j++) {
        float w = smax[j];
        rank += (w > v || (w == v && j < tid)) ? 1 : 0;
    }
    if (rank == 31) Lrow[r] = v;
}

// ---------------------------------------------------------------------------
// Pass 2: recompute GEMM (bit-identical acc), emit candidate cols >= L-eps.
// ---------------------------------------------------------------------------
__global__ __launch_bounds__(256)
void k_cand(const unsigned short* __restrict__ znb, const float* __restrict__ Lrow,
            int* __restrict__ ccnt, int* __restrict__ ccol)
{
    __shared__ float Lsh[128];
    const int tid  = threadIdx.x;
    const int lane = tid & 63;
    const int wv   = tid >> 6;
    const int am0  = blockIdx.x * 128;
    const int bn0  = blockIdx.y * 128;
    const int mq   = (wv & 1) * 64;
    const int nq   = (wv >> 1) * 64;
    const int lm   = lane & 15;
    const int lk   = lane >> 4;

    if (tid < 128) Lsh[tid] = Lrow[am0 + tid] - 1e-3f;   // wide safety margin
    __syncthreads();

    floatx4 acc[4][4];
    gemm128(znb, am0, bn0, lane, wv, acc);

    #pragma unroll
    for (int mt = 0; mt < 4; mt++)
        #pragma unroll
        for (int rg = 0; rg < 4; rg++) {
            int m = mq + mt * 16 + lk * 4 + rg;
            float Lr = Lsh[m];
            int row = am0 + m;
            #pragma unroll
            for (int nt = 0; nt < 4; nt++) {
                float v = acc[mt][nt][rg];
                if (v >= Lr) {
                    int p = atomicAdd(&ccnt[row], 1);
                    if (p < CAP) ccol[(size_t)row * CAP + p] = bn0 + nq + nt * 16 + lm;
                }
            }
        }
}

// ---------------------------------------------------------------------------
// Final: fp64 re-rank of all candidates -> exact top-17; emits nbr + deg.
// ---------------------------------------------------------------------------
__global__ __launch_bounds__(256)
void k_topk2(const int* __restrict__ ccnt, const int* __restrict__ ccol,
             const double* __restrict__ zn64, const float* __restrict__ zn32,
             int* __restrict__ nbr, int* __restrict__ deg, int use64)
{
    const int r = blockIdx.x;
    const int tid = threadIdx.x;
    __shared__ double q[CC];
    __shared__ double dv[CAP];
    __shared__ int    cs[CAP];

    int C = ccnt[r]; if (C > CAP) C = CAP;
    if (tid < CC)
        q[tid] = use64 ? zn64[(size_t)r * CC + tid] : (double)zn32[(size_t)r * CC + tid];
    if (tid < C) {
        int cx = ccol[(size_t)r * CAP + tid];
        cs[tid] = ((unsigned)cx < (unsigned)NN) ? cx : r;
    }
    __syncthreads();
    if (tid < C) {
        int cx = cs[tid];
        double s = 0.0;
        if (use64) {
            const double* zr = zn64 + (size_t)cx * CC;
            for (int k = 0; k < CC; k++) s += q[k] * zr[k];
        } else {
            const float* zr = zn32 + (size_t)cx * CC;
            for (int k = 0; k < CC; k++) s += q[k] * (double)zr[k];
        }
        dv[tid] = s;
    }
    __syncthreads();
    if (tid < C) {
        double v = dv[tid]; int ix = cs[tid];
        int rank = 0;
        for (int j = 0; j < C; j++) {
            double w = dv[j];
            rank += (w > v || (w == v && cs[j] < ix)) ? 1 : 0;
        }
        if (rank < KP1) {
            nbr[(size_t)r * KP1 + rank] = ix;
            if (ix != r && (unsigned)ix < (unsigned)NN) atomicAdd(&deg[ix], 1);
        }
    }
}

// ---------------------------------------------------------------------------
// Scan: one block, shuffle-based, 2 barriers.
// ---------------------------------------------------------------------------
__global__ __launch_bounds__(256)
void k_scan(const int* __restrict__ deg, int* __restrict__ rp, int* __restrict__ wp)
{
    const int tid  = threadIdx.x;
    const int lane = tid & 63;
    const int wv   = tid >> 6;
    const int base = tid * 64;

    int v[64];
    int sum = 0;
    #pragma unroll
    for (int i = 0; i < 16; i++) {
        int4 t = *(const int4*)&deg[base + i * 4];
        v[i*4+0] = t.x; v[i*4+1] = t.y; v[i*4+2] = t.z; v[i*4+3] = t.w;
        sum += t.x + t.y + t.z + t.w;
    }

    int inc = sum;
    #pragma unroll
    for (int off2 = 1; off2 < 64; off2 <<= 1) {
        int o = __shfl_up(inc, off2);
        if (lane >= off2) inc += o;
    }

    __shared__ int wtot[4];
    if (lane == 63) wtot[wv] = inc;
    __syncthreads();
    int woff = 0;
    for (int w = 0; w < wv; w++) woff += wtot[w];

    int run = woff + inc - sum;
    #pragma unroll
    for (int i = 0; i < 64; i++) {
        wp[base + i] = run;
        run += v[i];
        rp[base + i + 1] = run;
    }
    if (tid == 0) rp[0] = 0;
}

__global__ __launch_bounds__(256)
void k_fill(const int* __restrict__ nbr, int* __restrict__ wp, int* __restrict__ es)
{
    int e = blockIdx.x * 256 + threadIdx.x;
    if (e >= NN * KP1) return;
    int i = e / KP1;
    int dst = nbr[e];
    if (dst != i && (unsigned)dst < (unsigned)NN) {
        int pos = atomicAdd(&wp[dst], 1);
        if ((unsigned)pos < (unsigned)(NN * KP1)) es[pos] = i;
    }
}

// ---------------------------------------------------------------------------
// Mean of in-neighbors
// ---------------------------------------------------------------------------
__global__ __launch_bounds__(128)
void k_gather(const float* __restrict__ x, const int* __restrict__ rp,
              const int* __restrict__ es, float* __restrict__ meanb)
{
    int n = blockIdx.x, c = threadIdx.x;
    int b = rp[n], e2 = rp[n + 1];
    if (b < 0) b = 0;
    if (e2 > NN * KP1) e2 = NN * KP1;
    float acc = 0.f;
    int cnt = 0;
    for (int t = b; t < e2; t++) {
        int s = es[t];
        if ((unsigned)s < (unsigned)NN) { acc += x[(size_t)s * CC + c]; cnt++; }
    }
    meanb[(size_t)n * CC + c] = acc / fmaxf((float)cnt, 1.0f);
}

// ---------------------------------------------------------------------------
// SAGE layer: out = relu(a@Ws + mean@Wn + b), 8 nodes/block
// ---------------------------------------------------------------------------
__global__ __launch_bounds__(128)
void k_layer(const float* __restrict__ a, const float* __restrict__ mb,
             const float* __restrict__ Ws, const float* __restrict__ Wn,
             const float* __restrict__ bias, float* __restrict__ out)
{
    __shared__ float as[8][CC], ms[8][CC];
    const int tid = threadIdx.x;
    const int n0 = blockIdx.x * 8;
    #pragma unroll
    for (int m = 0; m < 8; m++) {
        as[m][tid] = a[(size_t)(n0 + m) * CC + tid];
        ms[m][tid] = mb[(size_t)(n0 + m) * CC + tid];
    }
    __syncthreads();
    float acc[8];
    #pragma unroll
    for (int m = 0; m < 8; m++) acc[m] = bias[tid];
    for (int j = 0; j < CC; j++) {
        float ws = Ws[j * CC + tid], wn = Wn[j * CC + tid];
        #pragma unroll
        for (int m = 0; m < 8; m++) acc[m] += as[m][j] * ws + ms[m][j] * wn;
    }
    #pragma unroll
    for (int m = 0; m < 8; m++)
        out[(size_t)(n0 + m) * CC + tid] = fmaxf(acc[m], 0.f);
}

// ---------------------------------------------------------------------------
// Head: out = h2 @ W_head + b_head, fp32 output
// ---------------------------------------------------------------------------
__global__ __launch_bounds__(128)
void k_head(const float* __restrict__ h2, const float* __restrict__ W,
            const float* __restrict__ bias, float* __restrict__ out)
{
    __shared__ float hsh[8][CC];
    const int tid = threadIdx.x;
    const int n0 = blockIdx.x * 8;
    #pragma unroll
    for (int m = 0; m < 8; m++) hsh[m][tid] = h2[(size_t)(n0 + m) * CC + tid];
    __syncthreads();
    float acc[8];
    #pragma unroll
    for (int m = 0; m < 8; m++) acc[m] = bias[tid];
    for (int j = 0; j < CC; j++) {
        float w = W[j * OO + tid];
        #pragma unroll
        for (int m = 0; m < 8; m++) acc[m] += hsh[m][j] * w;
    }
    #pragma unroll
    for (int m = 0; m < 8; m++)
        out[(size_t)(n0 + m) * OO + tid] = acc[m];
}

// ---------------------------------------------------------------------------
extern "C" void kernel_launch(void* const* d_in, const int* in_sizes, int n_in,
                              void* d_out, int out_size, void* d_ws, size_t ws_size,
                              hipStream_t stream)
{
    const float* x_raw      = (const float*)d_in[0];
    const float* eps        = (const float*)d_in[1];
    const float* col_logit  = (const float*)d_in[2];
    const float* type_logit = (const float*)d_in[3];
    const float* W_enc      = (const float*)d_in[4];
    const float* b_enc      = (const float*)d_in[5];
    const float* W_mu       = (const float*)d_in[6];
    const float* b_mu       = (const float*)d_in[7];
    const float* W_lv       = (const float*)d_in[8];
    const float* b_lv       = (const float*)d_in[9];
    const float* W_self1    = (const float*)d_in[10];
    const float* W_nbr1     = (const float*)d_in[11];
    const float* b1         = (const float*)d_in[12];
    const float* W_self2    = (const float*)d_in[13];
    const float* W_nbr2     = (const float*)d_in[14];
    const float* b2         = (const float*)d_in[15];
    const float* W_head     = (const float*)d_in[16];
    const float* b_head     = (const float*)d_in[17];
    float* out              = (float*)d_out;

    char* base = (char*)d_ws;
    size_t off = 0;
    auto alloc = [&](size_t bytes) { size_t o = off; off = (off + bytes + 255) & ~(size_t)255; return o; };

    const size_t MAT  = (size_t)NN * CC * 4;   // 8.39 MB

    float* z32    = (float*)(base + alloc(MAT));
    float* zn32   = (float*)(base + alloc(MAT));
    float* h1     = (float*)(base + alloc(MAT));
    float* h2     = (float*)(base + alloc(MAT));
    float* meanb  = (float*)(base + alloc(MAT));
    unsigned short* znb = (unsigned short*)(base + alloc((size_t)NN * CC * 2)); // 4.2 MB
    float* simmax = (float*)(base + alloc((size_t)NN * NT * 4));               // 16.8 MB
    float* Lrow   = (float*)(base + alloc((size_t)NN * 4));
    int*   ccnt   = (int*)(base + alloc((size_t)NN * 4));
    int*   ccol   = (int*)(base + alloc((size_t)NN * CAP * 4));                // 16.8 MB
    int*   nbr    = (int*)(base + alloc((size_t)NN * KP1 * 4));
    int*   deg    = (int*)(base + alloc((size_t)NN * 4));
    int*   rp     = (int*)(base + alloc((size_t)(NN + 1) * 4));
    int*   wp     = (int*)(base + alloc((size_t)NN * 4));
    int*   es     = (int*)(base + alloc((size_t)NN * KP1 * 4));
    size_t fixed = off;   // ~85 MB

    int use64 = (ws_size >= fixed + (size_t)NN * CC * 8 + 4096) ? 1 : 0;
    double* zn64 = nullptr;
    if (use64) zn64 = (double*)(base + alloc((size_t)NN * CC * 8));            // 16.8 MB

    k_init<<<(NN * KP1 + 255) / 256, 256, 0, stream>>>(deg, ccnt, nbr);

    k_pre<<<NN / 8, 128, 0, stream>>>(x_raw, eps, col_logit, type_logit,
                                      W_enc, b_enc, W_mu, b_mu, W_lv, b_lv,
                                      zn64, z32, zn32, znb, use64);

    dim3 gg(NN / 128, NN / 128);
    k_simmax<<<gg, 256, 0, stream>>>(znb, simmax);
    k_thresh<<<NN, 256, 0, stream>>>(simmax, Lrow);
    k_cand<<<gg, 256, 0, stream>>>(znb, Lrow, ccnt, ccol);
    k_topk2<<<NN, 256, 0, stream>>>(ccnt, ccol, zn64, zn32, nbr, deg, use64);

    k_scan<<<1, 256, 0, stream>>>(deg, rp, wp);
    int eb = (NN * KP1 + 255) / 256;
    k_fill<<<eb, 256, 0, stream>>>(nbr, wp, es);

    k_gather<<<NN, 128, 0, stream>>>(z32, rp, es, meanb);
    k_layer<<<NN / 8, 128, 0, stream>>>(z32, meanb, W_self1, W_nbr1, b1, h1);
    k_gather<<<NN, 128, 0, stream>>>(h1, rp, es, meanb);
    k_layer<<<NN / 8, 128, 0, stream>>>(h1, meanb, W_self2, W_nbr2, b2, h2);
    k_head<<<NN / 8, 128, 0, stream>>>(h2, W_head, b_head, out);

    (void)in_sizes; (void)n_in; (void)out_size;
}

// Round 15
// 857.654 us; speedup vs baseline: 1.2771x; 1.2771x over previous
//
#include <hip/hip_runtime.h>
#include <hip/hip_bf16.h>
#include <math.h>

constexpr int NN  = 16384;
constexpr int DD  = 64;
constexpr int CC  = 128;
constexpr int OO  = 128;
constexpr int KP1 = 17;
constexpr int NT  = 256;             // 64-col tiles per row
constexpr int CAP = 256;             // candidate cap per row

typedef __attribute__((ext_vector_type(8))) short short8;
typedef __attribute__((ext_vector_type(4))) float floatx4;

__device__ __forceinline__ float bf2f(unsigned short u) {
    union { unsigned u; float f; } c; c.u = ((unsigned)u) << 16; return c.f;
}
__device__ __forceinline__ unsigned short f2bf(float f) {
    union { float f; unsigned u; } c; c.f = f;
    unsigned b = c.u;
    return (unsigned short)((b + 0x7FFFu + ((b >> 16) & 1u)) >> 16);
}

// ---------------------------------------------------------------------------
// znbF: fragment-major bf16 layout. For node n, channel c:
//   tile t = n>>4, lm = n&15, kt = c>>5, lk = (c>>3)&3, e = c&7, lane = lk*16+lm
//   znbF[ ((t*4 + kt)*64 + lane)*8 + e ]
// A wave's fragment (t, kt) is 64 consecutive short8 = 1 KB contiguous.
// ---------------------------------------------------------------------------

// Shared 128x128 MFMA tile: identical code in k_simmax and k_cand ->
// bit-identical fp32 accumulators (MFMA deterministic, fixed chain order).
__device__ __forceinline__ void gemm128(const short8* __restrict__ fb,
                                        int am0, int bn0, int lane, int wv,
                                        floatx4 (&acc)[4][4])
{
    const int mq = (wv & 1) * 64;
    const int nq = (wv >> 1) * 64;
    const int ta0 = (am0 + mq) >> 4;      // A tile16 base
    const int tb0 = (bn0 + nq) >> 4;      // B tile16 base

    short8 af[4][4];   // [kt][mt]
    #pragma unroll
    for (int mt = 0; mt < 4; mt++)
        #pragma unroll
        for (int kt = 0; kt < 4; kt++)
            af[kt][mt] = fb[((size_t)(ta0 + mt) * 4 + kt) * 64 + lane];

    #pragma unroll
    for (int i = 0; i < 4; i++)
        #pragma unroll
        for (int j = 0; j < 4; j++) acc[i][j] = (floatx4){0.f, 0.f, 0.f, 0.f};

    #pragma unroll
    for (int nt = 0; nt < 4; nt++) {
        #pragma unroll
        for (int kt = 0; kt < 4; kt++) {
            short8 bf8 = fb[((size_t)(tb0 + nt) * 4 + kt) * 64 + lane];
            #pragma unroll
            for (int mt = 0; mt < 4; mt++)
                acc[mt][nt] = __builtin_amdgcn_mfma_f32_16x16x32_bf16(
                    af[kt][mt], bf8, acc[mt][nt], 0, 0, 0);
        }
    }
}

// ---------------------------------------------------------------------------
// Init: deg = 0, ccnt = 0, nbr = self
// ---------------------------------------------------------------------------
__global__ __launch_bounds__(256)
void k_init(int* __restrict__ deg, int* __restrict__ ccnt, int* __restrict__ nbr)
{
    int t = blockIdx.x * 256 + threadIdx.x;
    if (t < NN) { deg[t] = 0; ccnt[t] = 0; }
    if (t < NN * KP1) nbr[t] = t / KP1;
}

// ---------------------------------------------------------------------------
// Preprocess: 8 nodes/block, 128 threads (thread = channel), fp64 math.
// Emits zn64 (optional), z32, zn32, and znbF (fragment-major bf16).
// ---------------------------------------------------------------------------
__global__ __launch_bounds__(128)
void k_pre(const float* __restrict__ x_raw, const float* __restrict__ eps,
           const float* __restrict__ col_logit, const float* __restrict__ type_logit,
           const float* __restrict__ W_enc, const float* __restrict__ b_enc,
           const float* __restrict__ W_mu, const float* __restrict__ b_mu,
           const float* __restrict__ W_lv, const float* __restrict__ b_lv,
           double* __restrict__ zn64, float* __restrict__ z32, float* __restrict__ zn32,
           unsigned short* __restrict__ znbF, int use64)
{
    const int tid = threadIdx.x;
    const int n0  = blockIdx.x * 8;
    __shared__ double xg[8][DD];
    __shared__ double hs[8][CC];
    __shared__ double zs[8][CC];
    __shared__ double part[8][16];
    __shared__ double rs_s[8];
    __shared__ double gcol[DD];

    if (tid < DD) {
        double l = (double)col_logit[tid];
        double s = 1.0 / (1.0 + exp(-l * 0.5));
        gcol[tid] = fmin(fmax(s * 1.2 - 0.1, 0.0), 1.0);
    }
    __syncthreads();

    #pragma unroll
    for (int rpt = 0; rpt < 4; rpt++) {
        int idx = tid + rpt * 128;
        int m = idx >> 6, d = idx & 63;
        xg[m][d] = (double)x_raw[(size_t)(n0 + m) * DD + d] * gcol[d];
    }
    __syncthreads();

    double tg;
    {
        double l = (double)type_logit[0];
        double s = 1.0 / (1.0 + exp(-l * 0.5));
        tg = fmin(fmax(s * 1.2 - 0.1, 0.0), 1.0);
    }

    double h[8];
    #pragma unroll
    for (int m = 0; m < 8; m++) h[m] = (double)b_enc[tid];
    for (int d = 0; d < DD; d++) {
        double w = (double)W_enc[d * CC + tid];
        #pragma unroll
        for (int m = 0; m < 8; m++) h[m] += xg[m][d] * w;
    }
    #pragma unroll
    for (int m = 0; m < 8; m++) hs[m][tid] = h[m] * tg;
    __syncthreads();

    double mu[8], lv[8];
    #pragma unroll
    for (int m = 0; m < 8; m++) { mu[m] = (double)b_mu[tid]; lv[m] = (double)b_lv[tid]; }
    for (int j = 0; j < CC; j++) {
        double wm = (double)W_mu[j * CC + tid];
        double wl = (double)W_lv[j * CC + tid];
        #pragma unroll
        for (int m = 0; m < 8; m++) { double hj = hs[m][j]; mu[m] += hj * wm; lv[m] += hj * wl; }
    }
    #pragma unroll
    for (int m = 0; m < 8; m++) {
        double l = fmin(fmax(lv[m], -10.0), 10.0);
        zs[m][tid] = mu[m] + (double)eps[(size_t)(n0 + m) * CC + tid] * exp(0.5 * l);
    }
    __syncthreads();

    {
        int m = tid >> 4, t = tid & 15;
        double s = 0.0;
        for (int c = t; c < CC; c += 16) { double z = zs[m][c]; s += z * z; }
        part[m][t] = s;
    }
    __syncthreads();
    if (tid < 8) {
        double s = 0.0;
        for (int t = 0; t < 16; t++) s += part[tid][t];
        rs_s[tid] = 1.0 / sqrt(s + 1e-12);
    }
    __syncthreads();

    const int c  = tid;
    const int kt = c >> 5, lk = (c >> 3) & 3, e = c & 7;
    #pragma unroll
    for (int m = 0; m < 8; m++) {
        int n = n0 + m;
        double z  = zs[m][tid];
        double zn = z * rs_s[m];
        size_t o  = (size_t)n * CC + tid;
        if (use64) zn64[o] = zn;
        z32[o]  = (float)z;
        float znf = (float)zn;
        zn32[o] = znf;
        size_t fo = ((size_t)((n >> 4) * 4 + kt) * 64 + lk * 16 + (n & 15)) * 8 + e;
        znbF[fo] = f2bf(znf);
    }
}

// ---------------------------------------------------------------------------
// Pass 1: tile maxes only (raw fp32 acc). Grid (128,128).
// ---------------------------------------------------------------------------
__global__ __launch_bounds__(256)
void k_simmax(const unsigned short* __restrict__ znbF, float* __restrict__ simmax)
{
    const int tid  = threadIdx.x;
    const int lane = tid & 63;
    const int wv   = tid >> 6;
    const int am0  = blockIdx.x * 128;
    const int bn0  = blockIdx.y * 128;
    const int mq   = (wv & 1) * 64;
    const int lm   = lane & 15;
    const int lk   = lane >> 4;

    floatx4 acc[4][4];
    gemm128((const short8*)znbF, am0, bn0, lane, wv, acc);

    #pragma unroll
    for (int mt = 0; mt < 4; mt++)
        #pragma unroll
        for (int rg = 0; rg < 4; rg++) {
            int m = mq + mt * 16 + lk * 4 + rg;
            float mx = acc[mt][0][rg];
            #pragma unroll
            for (int nt = 1; nt < 4; nt++) mx = fmaxf(mx, acc[mt][nt][rg]);
            #pragma unroll
            for (int s = 1; s < 16; s <<= 1) mx = fmaxf(mx, __shfl_xor(mx, s));
            if (lm == 0) {
                int row = am0 + m;
                int gtile = blockIdx.y * 2 + (wv >> 1);
                simmax[(size_t)row * NT + gtile] = mx;
            }
        }
}

// ---------------------------------------------------------------------------
// L[row] = 32nd-largest tile max (covers the acc-top-32; fp64 margin to the
// true top-17 ~1.8e-2 >> bf16-acc noise ~1e-3).
// ---------------------------------------------------------------------------
__global__ __launch_bounds__(256)
void k_thresh(const float* __restrict__ simmax, float* __restrict__ Lrow)
{
    const int r = blockIdx.x;
    const int tid = threadIdx.x;
    __shared__ float smax[NT];
    smax[tid] = simmax[(size_t)r * NT + tid];
    __syncthreads();
    float v = smax[tid];
    int rank = 0;
    for (int j = 0; j < NT; j++) {
        float w = smax[j];
        rank += (w > v || (w == v && j < tid)) ? 1 : 0;
    }
    if (rank == 31) Lrow[r] = v;
}

// ---------------------------------------------------------------------------
// Pass 2: recompute GEMM (bit-identical acc), emit candidate cols >= L-eps.
// ---------------------------------------------------------------------------
__global__ __launch_bounds__(256)
void k_cand(const unsigned short* __restrict__ znbF, const float* __restrict__ Lrow,
            int* __restrict__ ccnt, int* __restrict__ ccol)
{
    __shared__ float Lsh[128];
    const int tid  = threadIdx.x;
    const int lane = tid & 63;
    const int wv   = tid >> 6;
    const int am0  = blockIdx.x * 128;
    const int bn0  = blockIdx.y * 128;
    const int mq   = (wv & 1) * 64;
    const int nq   = (wv >> 1) * 64;
    const int lm   = lane & 15;
    const int lk   = lane >> 4;

    if (tid < 128) Lsh[tid] = Lrow[am0 + tid] - 1e-3f;   // wide safety margin
    __syncthreads();

    floatx4 acc[4][4];
    gemm128((const short8*)znbF, am0, bn0, lane, wv, acc);

    #pragma unroll
    for (int mt = 0; mt < 4; mt++)
        #pragma unroll
        for (int rg = 0; rg < 4; rg++) {
            int m = mq + mt * 16 + lk * 4 + rg;
            float Lr = Lsh[m];
            int row = am0 + m;
            #pragma unroll
            for (int nt = 0; nt < 4; nt++) {
                float v = acc[mt][nt][rg];
                if (v >= Lr) {
                    int p = atomicAdd(&ccnt[row], 1);
                    if (p < CAP) ccol[(size_t)row * CAP + p] = bn0 + nq + nt * 16 + lm;
                }
            }
        }
}

// ---------------------------------------------------------------------------
// Final: fp64 re-rank of all candidates -> exact top-17; emits nbr + deg.
// ---------------------------------------------------------------------------
__global__ __launch_bounds__(256)
void k_topk2(const int* __restrict__ ccnt, const int* __restrict__ ccol,
             const double* __restrict__ zn64, const float* __restrict__ zn32,
             int* __restrict__ nbr, int* __restrict__ deg, int use64)
{
    const int r = blockIdx.x;
    const int tid = threadIdx.x;
    __shared__ double q[CC];
    __shared__ double dv[CAP];
    __shared__ int    cs[CAP];

    int C = ccnt[r]; if (C > CAP) C = CAP;
    if (tid < CC)
        q[tid] = use64 ? zn64[(size_t)r * CC + tid] : (double)zn32[(size_t)r * CC + tid];
    if (tid < C) {
        int cx = ccol[(size_t)r * CAP + tid];
        cs[tid] = ((unsigned)cx < (unsigned)NN) ? cx : r;
    }
    __syncthreads();
    if (tid < C) {
        int cx = cs[tid];
        double s = 0.0;
        if (use64) {
            const double* zr = zn64 + (size_t)cx * CC;
            for (int k = 0; k < CC; k++) s += q[k] * zr[k];
        } else {
            const float* zr = zn32 + (size_t)cx * CC;
            for (int k = 0; k < CC; k++) s += q[k] * (double)zr[k];
        }
        dv[tid] = s;
    }
    __syncthreads();
    if (tid < C) {
        double v = dv[tid]; int ix = cs[tid];
        int rank = 0;
        for (int j = 0; j < C; j++) {
            double w = dv[j];
            rank += (w > v || (w == v && cs[j] < ix)) ? 1 : 0;
        }
        if (rank < KP1) {
            nbr[(size_t)r * KP1 + rank] = ix;
            if (ix != r && (unsigned)ix < (unsigned)NN) atomicAdd(&deg[ix], 1);
        }
    }
}

// ---------------------------------------------------------------------------
// Scan: one block, shuffle-based, 2 barriers.
// ---------------------------------------------------------------------------
__global__ __launch_bounds__(256)
void k_scan(const int* __restrict__ deg, int* __restrict__ rp, int* __restrict__ wp)
{
    const int tid  = threadIdx.x;
    const int lane = tid & 63;
    const int wv   = tid >> 6;
    const int base = tid * 64;

    int v[64];
    int sum = 0;
    #pragma unroll
    for (int i = 0; i < 16; i++) {
        int4 t = *(const int4*)&deg[base + i * 4];
        v[i*4+0] = t.x; v[i*4+1] = t.y; v[i*4+2] = t.z; v[i*4+3] = t.w;
        sum += t.x + t.y + t.z + t.w;
    }

    int inc = sum;
    #pragma unroll
    for (int off2 = 1; off2 < 64; off2 <<= 1) {
        int o = __shfl_up(inc, off2);
        if (lane >= off2) inc += o;
    }

    __shared__ int wtot[4];
    if (lane == 63) wtot[wv] = inc;
    __syncthreads();
    int woff = 0;
    for (int w = 0; w < wv; w++) woff += wtot[w];

    int run = woff + inc - sum;
    #pragma unroll
    for (int i = 0; i < 64; i++) {
        wp[base + i] = run;
        run += v[i];
        rp[base + i + 1] = run;
    }
    if (tid == 0) rp[0] = 0;
}

__global__ __launch_bounds__(256)
void k_fill(const int* __restrict__ nbr, int* __restrict__ wp, int* __restrict__ es)
{
    int e = blockIdx.x * 256 + threadIdx.x;
    if (e >= NN * KP1) return;
    int i = e / KP1;
    int dst = nbr[e];
    if (dst != i && (unsigned)dst < (unsigned)NN) {
        int pos = atomicAdd(&wp[dst], 1);
        if ((unsigned)pos < (unsigned)(NN * KP1)) es[pos] = i;
    }
}

// ---------------------------------------------------------------------------
// Mean of in-neighbors
// ---------------------------------------------------------------------------
__global__ __launch_bounds__(128)
void k_gather(const float* __restrict__ x, const int* __restrict__ rp,
              const int* __restrict__ es, float* __restrict__ meanb)
{
    int n = blockIdx.x, c = threadIdx.x;
    int b = rp[n], e2 = rp[n + 1];
    if (b < 0) b = 0;
    if (e2 > NN * KP1) e2 = NN * KP1;
    float acc = 0.f;
    int cnt = 0;
    for (int t = b; t < e2; t++) {
        int s = es[t];
        if ((unsigned)s < (unsigned)NN) { acc += x[(size_t)s * CC + c]; cnt++; }
    }
    meanb[(size_t)n * CC + c] = acc / fmaxf((float)cnt, 1.0f);
}

// ---------------------------------------------------------------------------
// SAGE layer: out = relu(a@Ws + mean@Wn + b), 8 nodes/block
// ---------------------------------------------------------------------------
__global__ __launch_bounds__(128)
void k_layer(const float* __restrict__ a, const float* __restrict__ mb,
             const float* __restrict__ Ws, const float* __restrict__ Wn,
             const float* __restrict__ bias, float* __restrict__ out)
{
    __shared__ float as[8][CC], ms[8][CC];
    const int tid = threadIdx.x;
    const int n0 = blockIdx.x * 8;
    #pragma unroll
    for (int m = 0; m < 8; m++) {
        as[m][tid] = a[(size_t)(n0 + m) * CC + tid];
        ms[m][tid] = mb[(size_t)(n0 + m) * CC + tid];
    }
    __syncthreads();
    float acc[8];
    #pragma unroll
    for (int m = 0; m < 8; m++) acc[m] = bias[tid];
    for (int j = 0; j < CC; j++) {
        float ws = Ws[j * CC + tid], wn = Wn[j * CC + tid];
        #pragma unroll
        for (int m = 0; m < 8; m++) acc[m] += as[m][j] * ws + ms[m][j] * wn;
    }
    #pragma unroll
    for (int m = 0; m < 8; m++)
        out[(size_t)(n0 + m) * CC + tid] = fmaxf(acc[m], 0.f);
}

// ---------------------------------------------------------------------------
// Head: out = h2 @ W_head + b_head, fp32 output
// ---------------------------------------------------------------------------
__global__ __launch_bounds__(128)
void k_head(const float* __restrict__ h2, const float* __restrict__ W,
            const float* __restrict__ bias, float* __restrict__ out)
{
    __shared__ float hsh[8][CC];
    const int tid = threadIdx.x;
    const int n0 = blockIdx.x * 8;
    #pragma unroll
    for (int m = 0; m < 8; m++) hsh[m][tid] = h2[(size_t)(n0 + m) * CC + tid];
    __syncthreads();
    float acc[8];
    #pragma unroll
    for (int m = 0; m < 8; m++) acc[m] = bias[tid];
    for (int j = 0; j < CC; j++) {
        float w = W[j * OO + tid];
        #pragma unroll
        for (int m = 0; m < 8; m++) acc[m] += hsh[m][j] * w;
    }
    #pragma unroll
    for (int m = 0; m < 8; m++)
        out[(size_t)(n0 + m) * OO + tid] = acc[m];
}

// ---------------------------------------------------------------------------
extern "C" void kernel_launch(void* const* d_in, const int* in_sizes, int n_in,
                              void* d_out, int out_size, void* d_ws, size_t ws_size,
                              hipStream_t stream)
{
    const float* x_raw      = (const float*)d_in[0];
    const float* eps        = (const float*)d_in[1];
    const float* col_logit  = (const float*)d_in[2];
    const float* type_logit = (const float*)d_in[3];
    const float* W_enc      = (const float*)d_in[4];
    const float* b_enc      = (const float*)d_in[5];
    const float* W_mu       = (const float*)d_in[6];
    const float* b_mu       = (const float*)d_in[7];
    const float* W_lv       = (const float*)d_in[8];
    const float* b_lv       = (const float*)d_in[9];
    const float* W_self1    = (const float*)d_in[10];
    const float* W_nbr1     = (const float*)d_in[11];
    const float* b1         = (const float*)d_in[12];
    const float* W_self2    = (const float*)d_in[13];
    const float* W_nbr2     = (const float*)d_in[14];
    const float* b2         = (const float*)d_in[15];
    const float* W_head     = (const float*)d_in[16];
    const float* b_head     = (const float*)d_in[17];
    float* out              = (float*)d_out;

    char* base = (char*)d_ws;
    size_t off = 0;
    auto alloc = [&](size_t bytes) { size_t o = off; off = (off + bytes + 255) & ~(size_t)255; return o; };

    const size_t MAT  = (size_t)NN * CC * 4;   // 8.39 MB

    float* z32    = (float*)(base + alloc(MAT));
    float* zn32   = (float*)(base + alloc(MAT));
    float* h1     = (float*)(base + alloc(MAT));
    float* h2     = (float*)(base + alloc(MAT));
    float* meanb  = (float*)(base + alloc(MAT));
    unsigned short* znbF = (unsigned short*)(base + alloc((size_t)NN * CC * 2)); // 4.2 MB
    float* simmax = (float*)(base + alloc((size_t)NN * NT * 4));               // 16.8 MB
    float* Lrow   = (float*)(base + alloc((size_t)NN * 4));
    int*   ccnt   = (int*)(base + alloc((size_t)NN * 4));
    int*   ccol   = (int*)(base + alloc((size_t)NN * CAP * 4));                // 16.8 MB
    int*   nbr    = (int*)(base + alloc((size_t)NN * KP1 * 4));
    int*   deg    = (int*)(base + alloc((size_t)NN * 4));
    int*   rp     = (int*)(base + alloc((size_t)(NN + 1) * 4));
    int*   wp     = (int*)(base + alloc((size_t)NN * 4));
    int*   es     = (int*)(base + alloc((size_t)NN * KP1 * 4));
    size_t fixed = off;   // ~85 MB

    int use64 = (ws_size >= fixed + (size_t)NN * CC * 8 + 4096) ? 1 : 0;
    double* zn64 = nullptr;
    if (use64) zn64 = (double*)(base + alloc((size_t)NN * CC * 8));            // 16.8 MB

    k_init<<<(NN * KP1 + 255) / 256, 256, 0, stream>>>(deg, ccnt, nbr);

    k_pre<<<NN / 8, 128, 0, stream>>>(x_raw, eps, col_logit, type_logit,
                                      W_enc, b_enc, W_mu, b_mu, W_lv, b_lv,
                                      zn64, z32, zn32, znbF, use64);

    dim3 gg(NN / 128, NN / 128);
    k_simmax<<<gg, 256, 0, stream>>>(znbF, simmax);
    k_thresh<<<NN, 256, 0, stream>>>(simmax, Lrow);
    k_cand<<<gg, 256, 0, stream>>>(znbF, Lrow, ccnt, ccol);
    k_topk2<<<NN, 256, 0, stream>>>(ccnt, ccol, zn64, zn32, nbr, deg, use64);

    k_scan<<<1, 256, 0, stream>>>(deg, rp, wp);
    int eb = (NN * KP1 + 255) / 256;
    k_fill<<<eb, 256, 0, stream>>>(nbr, wp, es);

    k_gather<<<NN, 128, 0, stream>>>(z32, rp, es, meanb);
    k_layer<<<NN / 8, 128, 0, stream>>>(z32, meanb, W_self1, W_nbr1, b1, h1);
    k_gather<<<NN, 128, 0, stream>>>(h1, rp, es, meanb);
    k_layer<<<NN / 8, 128, 0, stream>>>(h1, meanb, W_self2, W_nbr2, b2, h2);
    k_head<<<NN / 8, 128, 0, stream>>>(h2, W_head, b_head, out);

    (void)in_sizes; (void)n_in; (void)out_size;
}